// Round 5
// baseline (228.643 us; speedup 1.0000x reference)
//
#include <hip/hip_runtime.h>

// DynamicRouting: grouped 1x1 conv (einsum bgihw,gfi->bgfhw) + 3-iter routing.
// B=16, G=8, FI=FO=64, HW=4096. Fully fused: con never touches HBM.
//
// R5: b-fragment retention. Phase 1 is a pure load burst: the wave's whole
// 16px x 512ch x-slice is loaded (128 dword loads, depth-2 cvt pipeline) and
// retained as fp16 B-fragments in just 64 VGPRs (bh[8][2]). con is then
// RECOMPUTED from registers in 3 MFMA passes (v0 / beta1->v1 / beta2->out)
// instead of being held in 128 acc regs. Max-live ~135 VGPR -> 3 waves/SIMD
// (vs R4's 2), and the load phase has zero dependent-use serialization.
// Recompute is bit-deterministic => numerics identical to R2-R4 (absmax .125).

typedef __attribute__((ext_vector_type(8))) _Float16 half8;
typedef __attribute__((ext_vector_type(4))) float f32x4;

#define NG   8
#define NFI  64
#define NFO  64
#define HW   4096

__device__ __forceinline__ float sigmoidf_fast(float v) {
    float e = __builtin_amdgcn_exp2f(-1.44269504088896f * v);
    return __builtin_amdgcn_rcpf(1.0f + e);
}

// ---- kernel 1: repack weights fp32 -> fragment-ordered (h,l) fp16 ----
// wbuf[((g*4+t)*4+c)*512 + lane*8 + j]:
//   c=0: h, k=q*8+j   c=1: h, k=32+q*8+j   c=2: l, k=q*8+j   c=3: l, k=32+q*8+j
__global__ __launch_bounds__(256)
void wconv_kernel(const float* __restrict__ w, _Float16* __restrict__ wbuf) {
    int V = blockIdx.x * 256 + threadIdx.x;   // 0..8191 fragments
    int g    = V >> 10;
    int t    = (V >> 8) & 3;
    int c    = (V >> 6) & 3;
    int lane = V & 63;
    int pl = lane & 15, q = lane >> 4;
    const float* src = w + g * (NFO * NFI) + (t * 16 + pl) * NFI + (c & 1) * 32 + q * 8;
    half8 o;
    #pragma unroll
    for (int j = 0; j < 8; ++j) {
        float f = src[j];
        _Float16 h = (_Float16)f;
        o[j] = (c >> 1) ? (_Float16)(f - (float)h) : h;
    }
    *(half8*)(wbuf + (size_t)V * 8) = o;
}

// ---- kernel 2: fused conv + routing, b-frag retention + 3-pass recompute ----
__global__ __launch_bounds__(256, 3)
void routing_kernel(const float* __restrict__ x,
                    const _Float16* __restrict__ wbuf,
                    const float* __restrict__ bias,
                    float* __restrict__ out) {
    const int tid  = threadIdx.x;
    const int b    = blockIdx.x >> 6;          // batch
    const int p0   = (blockIdx.x & 63) << 6;   // pixel tile base
    const int lane = tid & 63;
    const int wv   = tid >> 6;                 // wave -> 16-px slice
    const int pl   = lane & 15;                // MFMA n-lane (pixel)
    const int q    = lane >> 4;                // k-octet select / C row group
    const int pw   = wv * 16 + pl;             // pixel within tile

    const float* xg = x + (size_t)b * (NG * NFI) * HW + p0 + pw;

    // persistent fp16 B-fragments: bh[g][0] = k in q*8..q*8+7, [1] = +32
    half8 bh[NG][2];

#define XDECL(NM) float NM##0, NM##1, NM##2, NM##3, NM##4, NM##5, NM##6, NM##7, \
                        NM##8, NM##9, NM##10, NM##11, NM##12, NM##13, NM##14, NM##15;
#define XLOAD(G, NM)                                                         \
    {                                                                        \
        const float* p_ = xg + (size_t)((G) * 64 + q * 8) * HW;              \
        NM##0 = p_[(size_t)0 * HW];  NM##1 = p_[(size_t)1 * HW];             \
        NM##2 = p_[(size_t)2 * HW];  NM##3 = p_[(size_t)3 * HW];             \
        NM##4 = p_[(size_t)4 * HW];  NM##5 = p_[(size_t)5 * HW];             \
        NM##6 = p_[(size_t)6 * HW];  NM##7 = p_[(size_t)7 * HW];             \
        const float* p2_ = p_ + (size_t)32 * HW;                             \
        NM##8  = p2_[(size_t)0 * HW]; NM##9  = p2_[(size_t)1 * HW];          \
        NM##10 = p2_[(size_t)2 * HW]; NM##11 = p2_[(size_t)3 * HW];          \
        NM##12 = p2_[(size_t)4 * HW]; NM##13 = p2_[(size_t)5 * HW];          \
        NM##14 = p2_[(size_t)6 * HW]; NM##15 = p2_[(size_t)7 * HW];          \
    }
#define XCVT(G, NM)                                                          \
    {                                                                        \
        half8 t0, t1;                                                        \
        t0[0] = (_Float16)NM##0;  t0[1] = (_Float16)NM##1;                   \
        t0[2] = (_Float16)NM##2;  t0[3] = (_Float16)NM##3;                   \
        t0[4] = (_Float16)NM##4;  t0[5] = (_Float16)NM##5;                   \
        t0[6] = (_Float16)NM##6;  t0[7] = (_Float16)NM##7;                   \
        t1[0] = (_Float16)NM##8;  t1[1] = (_Float16)NM##9;                   \
        t1[2] = (_Float16)NM##10; t1[3] = (_Float16)NM##11;                  \
        t1[4] = (_Float16)NM##12; t1[5] = (_Float16)NM##13;                  \
        t1[6] = (_Float16)NM##14; t1[7] = (_Float16)NM##15;                  \
        bh[G][0] = t0; bh[G][1] = t1;                                        \
    }

    XDECL(XA) XDECL(XB)
    // phase 1: pure streaming burst, depth-2 cvt pipeline
    XLOAD(0, XA)
    XLOAD(1, XB)
    XCVT(0, XA) XLOAD(2, XA)
    XCVT(1, XB) XLOAD(3, XB)
    XCVT(2, XA) XLOAD(4, XA)
    XCVT(3, XB) XLOAD(5, XB)
    XCVT(4, XA) XLOAD(6, XA)
    XCVT(5, XB) XLOAD(7, XB)
    XCVT(6, XA)
    XCVT(7, XB)
#undef XDECL
#undef XLOAD
#undef XCVT

    // recompute con[g] (16 regs) from retained fragments; w frags from L1/L2
#define CONGT(G, T, CV)                                                      \
    {                                                                        \
        const _Float16* wp_ = wbuf + (size_t)(G) * 8192 + (T) * 2048 + lane * 8; \
        half8 a0h = *(const half8*)(wp_);                                    \
        half8 a1h = *(const half8*)(wp_ + 512);                              \
        half8 a0l = *(const half8*)(wp_ + 1024);                             \
        half8 a1l = *(const half8*)(wp_ + 1536);                             \
        CV = __builtin_amdgcn_mfma_f32_16x16x32_f16(a0h, bh[G][0], CV, 0, 0, 0); \
        CV = __builtin_amdgcn_mfma_f32_16x16x32_f16(a1h, bh[G][1], CV, 0, 0, 0); \
        CV = __builtin_amdgcn_mfma_f32_16x16x32_f16(a0l, bh[G][0], CV, 0, 0, 0); \
        CV = __builtin_amdgcn_mfma_f32_16x16x32_f16(a1l, bh[G][1], CV, 0, 0, 0); \
    }
#define CONG(G)                                                              \
    c0 = (f32x4){0.f,0.f,0.f,0.f}; c1 = (f32x4){0.f,0.f,0.f,0.f};            \
    c2 = (f32x4){0.f,0.f,0.f,0.f}; c3 = (f32x4){0.f,0.f,0.f,0.f};            \
    CONGT(G, 0, c0) CONGT(G, 1, c1) CONGT(G, 2, c2) CONGT(G, 3, c3)

    f32x4 c0, c1, c2, c3;

    // ---- pass A: v0[f] = 0.5 * sum_g con[g][f] ----
    f32x4 v0[4];
    #pragma unroll
    for (int t = 0; t < 4; ++t) v0[t] = (f32x4){0.f,0.f,0.f,0.f};
#define PASSA(G)                                                             \
    {                                                                        \
        CONG(G)                                                              \
        _Pragma("unroll")                                                    \
        for (int r = 0; r < 4; ++r) {                                        \
            v0[0][r] += c0[r]; v0[1][r] += c1[r];                            \
            v0[2][r] += c2[r]; v0[3][r] += c3[r];                            \
        }                                                                    \
    }
    PASSA(0) PASSA(1) PASSA(2) PASSA(3) PASSA(4) PASSA(5) PASSA(6) PASSA(7)
    #pragma unroll
    for (int t = 0; t < 4; ++t)
        #pragma unroll
        for (int r = 0; r < 4; ++r) v0[t][r] *= 0.5f;

    // ---- pass B: beta1[g] = sum_f v0*con ; v1[f] = sum_g a1*con ----
    float beta[NG];
    f32x4 v1[4];
    #pragma unroll
    for (int t = 0; t < 4; ++t) v1[t] = (f32x4){0.f,0.f,0.f,0.f};
#define PASSB(G)                                                             \
    {                                                                        \
        CONG(G)                                                              \
        float s = 0.f;                                                       \
        _Pragma("unroll")                                                    \
        for (int r = 0; r < 4; ++r)                                          \
            s += v0[0][r]*c0[r] + v0[1][r]*c1[r] + v0[2][r]*c2[r] + v0[3][r]*c3[r]; \
        s += __shfl_xor(s, 16); s += __shfl_xor(s, 32);                      \
        beta[G] = s;                                                         \
        float al = sigmoidf_fast(s);                                         \
        _Pragma("unroll")                                                    \
        for (int r = 0; r < 4; ++r) {                                        \
            v1[0][r] += al*c0[r]; v1[1][r] += al*c1[r];                      \
            v1[2][r] += al*c2[r]; v1[3][r] += al*c3[r];                      \
        }                                                                    \
    }
    PASSB(0) PASSB(1) PASSB(2) PASSB(3) PASSB(4) PASSB(5) PASSB(6) PASSB(7)

    // ---- pass C: beta2 = beta1 + sum_f v1*con ; out = sum_g a2*con ----
    f32x4 o[4];
    #pragma unroll
    for (int t = 0; t < 4; ++t) o[t] = (f32x4){0.f,0.f,0.f,0.f};
#define PASSC(G)                                                             \
    {                                                                        \
        CONG(G)                                                              \
        float s = 0.f;                                                       \
        _Pragma("unroll")                                                    \
        for (int r = 0; r < 4; ++r)                                          \
            s += v1[0][r]*c0[r] + v1[1][r]*c1[r] + v1[2][r]*c2[r] + v1[3][r]*c3[r]; \
        s += __shfl_xor(s, 16); s += __shfl_xor(s, 32);                      \
        float al = sigmoidf_fast(beta[G] + s);                               \
        _Pragma("unroll")                                                    \
        for (int r = 0; r < 4; ++r) {                                        \
            o[0][r] += al*c0[r]; o[1][r] += al*c1[r];                        \
            o[2][r] += al*c2[r]; o[3][r] += al*c3[r];                        \
        }                                                                    \
    }
    PASSC(0) PASSC(1) PASSC(2) PASSC(3) PASSC(4) PASSC(5) PASSC(6) PASSC(7)

#undef PASSA
#undef PASSB
#undef PASSC
#undef CONG
#undef CONGT

    // ---- store: out[f] = o + bias[f] ----
    #pragma unroll
    for (int t = 0; t < 4; ++t)
        #pragma unroll
        for (int r = 0; r < 4; ++r) {
            int f = t * 16 + q * 4 + r;
            out[((size_t)(b * NFO + f)) * HW + p0 + pw] = o[t][r] + bias[f];
        }
}

extern "C" void kernel_launch(void* const* d_in, const int* in_sizes, int n_in,
                              void* d_out, int out_size, void* d_ws, size_t ws_size,
                              hipStream_t stream) {
    const float* x    = (const float*)d_in[0];
    const float* w    = (const float*)d_in[1];
    const float* bias = (const float*)d_in[2];
    float* out = (float*)d_out;
    _Float16* wbuf = (_Float16*)d_ws;   // 128 KiB fragment-ordered (h,l) weights

    wconv_kernel<<<32, 256, 0, stream>>>(w, wbuf);
    routing_kernel<<<1024, 256, 0, stream>>>(x, wbuf, bias, out);
}

// Round 6
// 216.969 us; speedup vs baseline: 1.0538x; 1.0538x over previous
//
#include <hip/hip_runtime.h>

// DynamicRouting: grouped 1x1 conv (einsum bgihw,gfi->bgfhw) + 3-iter routing.
// B=16, G=8, FI=FO=64, HW=4096. Fully fused: con never touches HBM.
//
// R6: G-split waves + LDS reduction. Block = 512 thr / 32 px: 8 waves =
// 4 g-pair waves x 2 px-halves. Each wave holds con for only 2 groups
// (acc 32 regs, vs 128 in R4) -> 4 waves/SIMD instead of 2. The cross-g
// routing sums (v0, v1, out) are 3 LDS f32x4 reduction rounds across the
// 4 g-pair waves (16 B/lane linear -> conflict-free b128), ping-pong
// regions + 3 barriers. Numerics identical to R2-R5 (absmax 0.125):
// fp16 x, w split h+l fp16, fp32 everywhere else.

typedef __attribute__((ext_vector_type(8))) _Float16 half8;
typedef __attribute__((ext_vector_type(4))) float f32x4;

#define NG   8
#define NFI  64
#define NFO  64
#define HW   4096

__device__ __forceinline__ float sigmoidf_fast(float v) {
    float e = __builtin_amdgcn_exp2f(-1.44269504088896f * v);
    return __builtin_amdgcn_rcpf(1.0f + e);
}

// ---- kernel 1: repack weights fp32 -> fragment-ordered (h,l) fp16 ----
// wbuf[((g*4+t)*4+c)*512 + lane*8 + j]:
//   c=0: h, k=q*8+j   c=1: h, k=32+q*8+j   c=2: l, k=q*8+j   c=3: l, k=32+q*8+j
__global__ __launch_bounds__(256)
void wconv_kernel(const float* __restrict__ w, _Float16* __restrict__ wbuf) {
    int V = blockIdx.x * 256 + threadIdx.x;   // 0..8191 fragments
    int g    = V >> 10;
    int t    = (V >> 8) & 3;
    int c    = (V >> 6) & 3;
    int lane = V & 63;
    int pl = lane & 15, q = lane >> 4;
    const float* src = w + g * (NFO * NFI) + (t * 16 + pl) * NFI + (c & 1) * 32 + q * 8;
    half8 o;
    #pragma unroll
    for (int j = 0; j < 8; ++j) {
        float f = src[j];
        _Float16 h = (_Float16)f;
        o[j] = (c >> 1) ? (_Float16)(f - (float)h) : h;
    }
    *(half8*)(wbuf + (size_t)V * 8) = o;
}

// ---- kernel 2: fused conv + routing, G-split + LDS reduce ----
__global__ __launch_bounds__(512, 4)
void routing_kernel(const float* __restrict__ x,
                    const _Float16* __restrict__ wbuf,
                    const float* __restrict__ bias,
                    float* __restrict__ out) {
    // [ph][parity][ (wg*4+t)*64 + q*16 + pl ] f32x4 tiles; 64 KiB total
    __shared__ f32x4 lds[4096];

    const int tid  = threadIdx.x;
    const int lane = tid & 63;
    const int wv   = tid >> 6;        // 0..7
    const int ph   = wv >> 2;         // pixel half (16 px each)
    const int wg   = wv & 3;          // g-pair: groups 2wg, 2wg+1
    const int pl   = lane & 15;       // MFMA n-lane (pixel)
    const int q    = lane >> 4;       // k-octet / C row group
    const int b    = blockIdx.x >> 7;
    const int p0   = (blockIdx.x & 127) << 5;
    const int px   = p0 + ph * 16 + pl;

    const float* xg = x + (size_t)b * (NG * NFI) * HW + px;

    // ---- phase 1: load x for groups 2wg, 2wg+1 (32 loads, one burst) ----
    float xa[16], xb[16];
    {
        const float* pA = xg + (size_t)((2 * wg)     * 64 + q * 8) * HW;
        const float* pB = xg + (size_t)((2 * wg + 1) * 64 + q * 8) * HW;
        #pragma unroll
        for (int j = 0; j < 8; ++j) {
            xa[j]     = pA[(size_t)j * HW];
            xa[8 + j] = pA[(size_t)(32 + j) * HW];
        }
        #pragma unroll
        for (int j = 0; j < 8; ++j) {
            xb[j]     = pB[(size_t)j * HW];
            xb[8 + j] = pB[(size_t)(32 + j) * HW];
        }
    }
    half8 bh[2][2];
    #pragma unroll
    for (int j = 0; j < 8; ++j) {
        bh[0][0][j] = (_Float16)xa[j];     bh[0][1][j] = (_Float16)xa[8 + j];
        bh[1][0][j] = (_Float16)xb[j];     bh[1][1][j] = (_Float16)xb[8 + j];
    }

    // ---- phase 2: con for the 2 local groups (32 MFMAs, 8 indep chains) ----
    f32x4 acc[2][4];
    #pragma unroll
    for (int gl = 0; gl < 2; ++gl)
        #pragma unroll
        for (int t = 0; t < 4; ++t)
            acc[gl][t] = (f32x4){0.f, 0.f, 0.f, 0.f};

    #pragma unroll
    for (int gl = 0; gl < 2; ++gl) {
        #pragma unroll
        for (int t = 0; t < 4; ++t) {
            const _Float16* wp = wbuf + (size_t)(2 * wg + gl) * 8192 + t * 2048 + lane * 8;
            half8 a0h = *(const half8*)(wp);
            half8 a1h = *(const half8*)(wp + 512);
            half8 a0l = *(const half8*)(wp + 1024);
            half8 a1l = *(const half8*)(wp + 1536);
            acc[gl][t] = __builtin_amdgcn_mfma_f32_16x16x32_f16(a0h, bh[gl][0], acc[gl][t], 0, 0, 0);
            acc[gl][t] = __builtin_amdgcn_mfma_f32_16x16x32_f16(a1h, bh[gl][1], acc[gl][t], 0, 0, 0);
            acc[gl][t] = __builtin_amdgcn_mfma_f32_16x16x32_f16(a0l, bh[gl][0], acc[gl][t], 0, 0, 0);
            acc[gl][t] = __builtin_amdgcn_mfma_f32_16x16x32_f16(a1l, bh[gl][1], acc[gl][t], 0, 0, 0);
        }
    }

    // ---- phase 3: routing with 3 cross-wave LDS reductions ----
    f32x4* LA = lds + ph * 2048;        // parity A
    f32x4* LB = LA + 1024;              // parity B
    const int slotQ = q * 16 + pl;      // lane-linear within a (wg,t) row

    // round 1: v0 = 0.5 * sum_g con
    #pragma unroll
    for (int t = 0; t < 4; ++t)
        LA[(wg * 4 + t) * 64 + slotQ] = acc[0][t] + acc[1][t];
    __syncthreads();
    f32x4 v0[4];
    #pragma unroll
    for (int t = 0; t < 4; ++t) {
        f32x4 s = LA[(0 * 4 + t) * 64 + slotQ];
        s += LA[(1 * 4 + t) * 64 + slotQ];
        s += LA[(2 * 4 + t) * 64 + slotQ];
        s += LA[(3 * 4 + t) * 64 + slotQ];
        v0[t] = s * 0.5f;
    }

    // beta1 for local groups: dot over f (16 local (t,r) + q-shfl)
    float s0 = 0.f, s1 = 0.f;
    #pragma unroll
    for (int t = 0; t < 4; ++t)
        #pragma unroll
        for (int r = 0; r < 4; ++r) {
            s0 += v0[t][r] * acc[0][t][r];
            s1 += v0[t][r] * acc[1][t][r];
        }
    s0 += __shfl_xor(s0, 16); s0 += __shfl_xor(s0, 32);
    s1 += __shfl_xor(s1, 16); s1 += __shfl_xor(s1, 32);
    const float beta0 = s0, beta1v = s1;
    float al0 = sigmoidf_fast(beta0);
    float al1 = sigmoidf_fast(beta1v);

    // round 2: v1 = sum_g alpha1*con
    #pragma unroll
    for (int t = 0; t < 4; ++t)
        LB[(wg * 4 + t) * 64 + slotQ] = al0 * acc[0][t] + al1 * acc[1][t];
    __syncthreads();
    f32x4 v1[4];
    #pragma unroll
    for (int t = 0; t < 4; ++t) {
        f32x4 s = LB[(0 * 4 + t) * 64 + slotQ];
        s += LB[(1 * 4 + t) * 64 + slotQ];
        s += LB[(2 * 4 + t) * 64 + slotQ];
        s += LB[(3 * 4 + t) * 64 + slotQ];
        v1[t] = s;
    }

    // beta2 = beta1 + dot(v1, con); alpha2
    s0 = 0.f; s1 = 0.f;
    #pragma unroll
    for (int t = 0; t < 4; ++t)
        #pragma unroll
        for (int r = 0; r < 4; ++r) {
            s0 += v1[t][r] * acc[0][t][r];
            s1 += v1[t][r] * acc[1][t][r];
        }
    s0 += __shfl_xor(s0, 16); s0 += __shfl_xor(s0, 32);
    s1 += __shfl_xor(s1, 16); s1 += __shfl_xor(s1, 32);
    al0 = sigmoidf_fast(beta0 + s0);
    al1 = sigmoidf_fast(beta1v + s1);

    // round 3: out = sum_g alpha2*con (each wave reads its t=wg quarter)
    #pragma unroll
    for (int t = 0; t < 4; ++t)
        LA[(wg * 4 + t) * 64 + slotQ] = al0 * acc[0][t] + al1 * acc[1][t];
    __syncthreads();
    f32x4 o = LA[(0 * 4 + wg) * 64 + slotQ];
    o += LA[(1 * 4 + wg) * 64 + slotQ];
    o += LA[(2 * 4 + wg) * 64 + slotQ];
    o += LA[(3 * 4 + wg) * 64 + slotQ];
    const f32x4 bv = *(const f32x4*)(bias + wg * 16 + q * 4);
    o += bv;

    // store: f = wg*16 + q*4 + r, px contiguous across pl (64B segments)
    float* op = out + ((size_t)(b * NFO + wg * 16 + q * 4)) * HW + px;
    #pragma unroll
    for (int r = 0; r < 4; ++r)
        op[(size_t)r * HW] = o[r];
}

extern "C" void kernel_launch(void* const* d_in, const int* in_sizes, int n_in,
                              void* d_out, int out_size, void* d_ws, size_t ws_size,
                              hipStream_t stream) {
    const float* x    = (const float*)d_in[0];
    const float* w    = (const float*)d_in[1];
    const float* bias = (const float*)d_in[2];
    float* out = (float*)d_out;
    _Float16* wbuf = (_Float16*)d_ws;   // 128 KiB fragment-ordered (h,l) weights

    wconv_kernel<<<32, 256, 0, stream>>>(w, wbuf);
    routing_kernel<<<2048, 512, 0, stream>>>(x, wbuf, bias, out);
}